// Round 18
// baseline (446.859 us; speedup 1.0000x reference)
//
#include <hip/hip_runtime.h>
#include <hip/hip_bf16.h>

// ---------------------------------------------------------------------------
// GCN 2-layer + edge dot logits, CSR-pull aggregation.
// agg[d] = dinv[d] * ( sum_{s in in(d)} hs[s] + hs[d] ) + b,  hs = (A@W)*dinv[row]
// Round 18: r17 + degree-sorted node permutation for the pulls (counting sort
// by degree; waves hold 16 equal-degree nodes -> no divergence waste).
// Tables XCD-chunk-transposed [c][N][16]; ushort col; atomic-free fill.
// ---------------------------------------------------------------------------

using ushort_t = unsigned short;

// count + per-edge rank within its dst segment (atomic returns old count)
__global__ void cnt_rank_k(const int* __restrict__ dst, int* __restrict__ cnt,
                           int* __restrict__ rank, int E) {
    int t = blockIdx.x * blockDim.x + threadIdx.x;
    int e = t * 4;
    if (e + 4 <= E) {
        int4 d4 = *reinterpret_cast<const int4*>(dst + e);
        int4 r4;
        r4.x = atomicAdd(&cnt[d4.x], 1);
        r4.y = atomicAdd(&cnt[d4.y], 1);
        r4.z = atomicAdd(&cnt[d4.z], 1);
        r4.w = atomicAdd(&cnt[d4.w], 1);
        *reinterpret_cast<int4*>(rank + e) = r4;   // coalesced
    } else {
        for (int i = e; i < E; i++) rank[i] = atomicAdd(&cnt[dst[i]], 1);
    }
}

// block scan over cnt + degree histogram (buckets min(deg,1023))
__global__ void scan1_k(const int* __restrict__ cnt, int* __restrict__ incl,
                        int* __restrict__ bsum, int* __restrict__ hist, int N) {
    __shared__ int sh[256];
    int i = blockIdx.x * 256 + threadIdx.x;
    int v = (i < N) ? cnt[i] : 0;
    sh[threadIdx.x] = v;
    __syncthreads();
#pragma unroll
    for (int off = 1; off < 256; off <<= 1) {
        int t = (threadIdx.x >= off) ? sh[threadIdx.x - off] : 0;
        __syncthreads();
        sh[threadIdx.x] += t;
        __syncthreads();
    }
    if (i < N) {
        incl[i] = sh[threadIdx.x];
        atomicAdd(&hist[min(v, 1023)], 1);
    }
    if (threadIdx.x == 255) bsum[blockIdx.x] = sh[255];
}

// exclusive scan of the 1024-bucket histogram -> hcur
__global__ __launch_bounds__(1024) void hscan_k(const int* __restrict__ hist,
                                                int* __restrict__ hcur) {
    __shared__ int sh[1024];
    int v = hist[threadIdx.x];
    sh[threadIdx.x] = v;
    __syncthreads();
#pragma unroll
    for (int off = 1; off < 1024; off <<= 1) {
        int t = (threadIdx.x >= off) ? sh[threadIdx.x - off] : 0;
        __syncthreads();
        sh[threadIdx.x] += t;
        __syncthreads();
    }
    hcur[threadIdx.x] = sh[threadIdx.x] - v;  // exclusive
}

// fused scan2+scan3 + perm scatter: rowptr/dinv writeback; perm = nodes in
// degree-sorted order (counting-sort scatter via hcur).
__global__ __launch_bounds__(256) void scan23_k(const int* __restrict__ cnt,
                                                const int* __restrict__ incl,
                                                const int* __restrict__ bsum,
                                                int* __restrict__ rowptr,
                                                float* __restrict__ dinv,
                                                int* __restrict__ hcur,
                                                int* __restrict__ perm,
                                                int N, int E, int NB) {
    __shared__ int sh[256];
    __shared__ int blockOff;
    int v = (threadIdx.x < NB) ? bsum[threadIdx.x] : 0;
    sh[threadIdx.x] = v;
    __syncthreads();
#pragma unroll
    for (int off = 1; off < 256; off <<= 1) {
        int t = (threadIdx.x >= off) ? sh[threadIdx.x - off] : 0;
        __syncthreads();
        sh[threadIdx.x] += t;
        __syncthreads();
    }
    if (threadIdx.x == blockIdx.x) blockOff = sh[threadIdx.x] - v;  // exclusive
    __syncthreads();
    int i = blockIdx.x * 256 + threadIdx.x;
    if (i < N) {
        int c = cnt[i];
        rowptr[i] = incl[i] - c + blockOff;
        dinv[i] = rsqrtf(1.0f + (float)c);  // +1 self-loop
        int pos = atomicAdd(&hcur[min(c, 1023)], 1);
        perm[pos] = i;
    }
    if (i == 0) rowptr[N] = E;
}

// ---------------------------------------------------------------------------
// GEMM body, BM=32, BK=16, 256 threads (conflict-free LDS maps).
// Output CHUNK-TRANSPOSED: OutT[chunk][N][16].
// ---------------------------------------------------------------------------
template <int BN, bool RELU>
__device__ __forceinline__ void gemm_body32(const float* __restrict__ A,
                                            const float* __restrict__ W,
                                            const float* __restrict__ dscale,
                                            float4* __restrict__ OutT,
                                            int M, int Nn, int row0,
                                            float (*As)[36], float (*Bs)[BN]) {
    constexpr int K = 128, BK = 16;
    constexpr int TN = BN / 16;  // 8 (BN=128) or 4 (BN=64)
    const int tid = threadIdx.x;
    const int tx = tid & 15, ty = tid >> 4;

    float acc[2][TN];
#pragma unroll
    for (int m = 0; m < 2; m++)
#pragma unroll
        for (int n = 0; n < TN; n++) acc[m][n] = 0.0f;

    for (int kt = 0; kt < K; kt += BK) {
        if (tid < 128) {
            int r = tid >> 2;
            int kq = (tid & 3) * 4;
            float4 av = make_float4(0.f, 0.f, 0.f, 0.f);
            int gr = row0 + r;
            if (gr < M)
                av = *reinterpret_cast<const float4*>(A + (size_t)gr * K + kt + kq);
            if (RELU) {
                av.x = fmaxf(av.x, 0.f); av.y = fmaxf(av.y, 0.f);
                av.z = fmaxf(av.z, 0.f); av.w = fmaxf(av.w, 0.f);
            }
            As[kq + 0][r] = av.x; As[kq + 1][r] = av.y;
            As[kq + 2][r] = av.z; As[kq + 3][r] = av.w;
        }
#pragma unroll
        for (int s = 0; s < (BK * BN) / (256 * 4); s++) {
            int f = s * 256 + tid;
            int brow = f / (BN / 4);
            int bcol = (f % (BN / 4)) * 4;
            float4 bv = *reinterpret_cast<const float4*>(W + (size_t)(kt + brow) * BN + bcol);
            *reinterpret_cast<float4*>(&Bs[brow][bcol]) = bv;
        }
        __syncthreads();

#pragma unroll
        for (int k = 0; k < BK; k++) {
            float2 a2 = *reinterpret_cast<const float2*>(&As[k][ty * 2]);
            float a[2] = {a2.x, a2.y};
            float b[TN];
            float4 b0 = *reinterpret_cast<const float4*>(&Bs[k][tx * 4]);
            b[0] = b0.x; b[1] = b0.y; b[2] = b0.z; b[3] = b0.w;
            if (TN == 8) {
                float4 b1 = *reinterpret_cast<const float4*>(&Bs[k][64 + tx * 4]);
                b[4] = b1.x; b[5] = b1.y; b[6] = b1.z; b[7] = b1.w;
            }
#pragma unroll
            for (int m = 0; m < 2; m++)
#pragma unroll
                for (int n = 0; n < TN; n++) acc[m][n] = fmaf(a[m], b[n], acc[m][n]);
        }
        __syncthreads();
    }

    const int chunk0 = tx >> 2;
    const int off = tx & 3;
#pragma unroll
    for (int m = 0; m < 2; m++) {
        int gr = row0 + ty * 2 + m;
        if (gr < M) {
            float dv = dscale[gr];
            float4 o0 = make_float4(acc[m][0] * dv, acc[m][1] * dv,
                                    acc[m][2] * dv, acc[m][3] * dv);
            OutT[((size_t)chunk0 * Nn + gr) * 4 + off] = o0;
            if (TN == 8) {
                float4 o1 = make_float4(acc[m][4] * dv, acc[m][5] * dv,
                                        acc[m][6] * dv, acc[m][7] * dv);
                OutT[((size_t)(4 + chunk0) * Nn + gr) * 4 + off] = o1;
            }
        }
    }
}

// ---------------------------------------------------------------------------
// FUSED (range-split): blocks [0,gemmBlocks) = GEMM1 -> hsT chunked; rest =
// atomic-free CSR fill: colu[rowptr[dst]+rank] = (ushort)src.
// ---------------------------------------------------------------------------
__global__ __launch_bounds__(256) void gemm1_fill_k(const float* __restrict__ A,
                                                    const float* __restrict__ W,
                                                    const float* __restrict__ dscale,
                                                    float4* __restrict__ OutT,
                                                    int M, int Nn,
                                                    const int* __restrict__ src,
                                                    const int* __restrict__ dst,
                                                    const int* __restrict__ rowptr,
                                                    const int* __restrict__ rank,
                                                    ushort_t* __restrict__ colu, int E,
                                                    int gemmBlocks) {
    __shared__ float As[16][36];
    __shared__ float Bs[16][128];
    int g = (int)blockIdx.x;
    if (g >= gemmBlocks) {
        int t = (g - gemmBlocks) * 256 + threadIdx.x;
        int e = t * 4;
        if (e + 4 <= E) {
            int4 s4 = *reinterpret_cast<const int4*>(src + e);
            int4 d4 = *reinterpret_cast<const int4*>(dst + e);
            int4 r4 = *reinterpret_cast<const int4*>(rank + e);
            colu[rowptr[d4.x] + r4.x] = (ushort_t)s4.x;
            colu[rowptr[d4.y] + r4.y] = (ushort_t)s4.y;
            colu[rowptr[d4.z] + r4.z] = (ushort_t)s4.z;
            colu[rowptr[d4.w] + r4.w] = (ushort_t)s4.w;
        } else {
            for (int i = e; i < E; i++)
                colu[rowptr[dst[i]] + rank[i]] = (ushort_t)src[i];
        }
        return;
    }
    gemm_body32<128, false>(A, W, dscale, OutT, M, Nn, g * 32, As, Bs);
}

__global__ __launch_bounds__(256) void gemm2_k(const float* __restrict__ A,
                                               const float* __restrict__ W,
                                               const float* __restrict__ dscale,
                                               float4* __restrict__ OutT,
                                               int M, int Nn) {
    __shared__ float As[16][36];
    __shared__ float Bs[16][64];
    gemm_body32<64, true>(A, W, dscale, OutT, M, Nn, (int)blockIdx.x * 32, As, Bs);
}

// ---------------------------------------------------------------------------
// Chunked pull body: 4 lanes per node; 8-deep unrolled gather with next-block
// index prefetch.
// ---------------------------------------------------------------------------
__device__ __forceinline__ float4 pull_body(const int* __restrict__ rowptr,
                                            const ushort_t* __restrict__ colu,
                                            const float4* __restrict__ T,
                                            size_t cb, int v, int j) {
    int p0 = rowptr[v], p1 = rowptr[v + 1];
    float4 acc = T[(cb + v) * 4 + j];  // self row slice
    int p = p0;

    if (p + 8 <= p1) {
        int n0 = colu[p + 0], n1 = colu[p + 1], n2 = colu[p + 2], n3 = colu[p + 3];
        int n4 = colu[p + 4], n5 = colu[p + 5], n6 = colu[p + 6], n7 = colu[p + 7];
        for (;;) {
            bool nxt = (p + 16 <= p1);
            int m0, m1, m2, m3, m4, m5, m6, m7;
            if (nxt) {
                m0 = colu[p + 8];  m1 = colu[p + 9];  m2 = colu[p + 10]; m3 = colu[p + 11];
                m4 = colu[p + 12]; m5 = colu[p + 13]; m6 = colu[p + 14]; m7 = colu[p + 15];
            }
            float4 g0 = T[(cb + n0) * 4 + j];
            float4 g1 = T[(cb + n1) * 4 + j];
            float4 g2 = T[(cb + n2) * 4 + j];
            float4 g3 = T[(cb + n3) * 4 + j];
            float4 g4 = T[(cb + n4) * 4 + j];
            float4 g5 = T[(cb + n5) * 4 + j];
            float4 g6 = T[(cb + n6) * 4 + j];
            float4 g7 = T[(cb + n7) * 4 + j];
            acc.x += ((g0.x + g1.x) + (g2.x + g3.x)) + ((g4.x + g5.x) + (g6.x + g7.x));
            acc.y += ((g0.y + g1.y) + (g2.y + g3.y)) + ((g4.y + g5.y) + (g6.y + g7.y));
            acc.z += ((g0.z + g1.z) + (g2.z + g3.z)) + ((g4.z + g5.z) + (g6.z + g7.z));
            acc.w += ((g0.w + g1.w) + (g2.w + g3.w)) + ((g4.w + g5.w) + (g6.w + g7.w));
            p += 8;
            if (!nxt) break;
            n0 = m0; n1 = m1; n2 = m2; n3 = m3;
            n4 = m4; n5 = m5; n6 = m6; n7 = m7;
        }
    }
    for (; p + 4 <= p1; p += 4) {
        int u0 = colu[p], u1 = colu[p + 1], u2 = colu[p + 2], u3 = colu[p + 3];
        float4 a = T[(cb + u0) * 4 + j];
        float4 b = T[(cb + u1) * 4 + j];
        float4 c = T[(cb + u2) * 4 + j];
        float4 d = T[(cb + u3) * 4 + j];
        acc.x += (a.x + b.x) + (c.x + d.x);
        acc.y += (a.y + b.y) + (c.y + d.y);
        acc.z += (a.z + b.z) + (c.z + d.z);
        acc.w += (a.w + b.w) + (c.w + d.w);
    }
    for (; p < p1; p++) {
        float4 a = T[(cb + colu[p]) * 4 + j];
        acc.x += a.x; acc.y += a.y; acc.z += a.z; acc.w += a.w;
    }
    return acc;
}

// pull128: blockIdx = g*8 + c -> chunk c (XCD c). Nodes via degree-sorted perm.
// Output agg1 LINEAR [N][128].
__global__ __launch_bounds__(256) void pull128c_k(const int* __restrict__ rowptr,
                                                  const ushort_t* __restrict__ colu,
                                                  const int* __restrict__ perm,
                                                  const float4* __restrict__ hsT,
                                                  const float* __restrict__ dinv,
                                                  const float4* __restrict__ bias4,
                                                  float4* __restrict__ out4, int N) {
    int c = (int)(blockIdx.x & 7);
    int g = (int)(blockIdx.x >> 3);
    int idx = g * 64 + (int)(threadIdx.x >> 2);
    if (idx >= N) return;
    int v = perm[idx];
    int j = threadIdx.x & 3;
    float4 acc = pull_body(rowptr, colu, hsT, (size_t)c * N, v, j);
    float dv = dinv[v];
    float4 bv = bias4[c * 4 + j];
    out4[(size_t)v * 32 + c * 4 + j] =
        make_float4(fmaf(acc.x, dv, bv.x), fmaf(acc.y, dv, bv.y),
                    fmaf(acc.z, dv, bv.z), fmaf(acc.w, dv, bv.w));
}

// pull64: blockIdx = g*4 + c (slice on XCDs c,c+4). Nodes via perm.
// Output agg2T CHUNKED [4][N][16].
__global__ __launch_bounds__(256) void pull64c_k(const int* __restrict__ rowptr,
                                                 const ushort_t* __restrict__ colu,
                                                 const int* __restrict__ perm,
                                                 const float4* __restrict__ g2T,
                                                 const float* __restrict__ dinv,
                                                 const float4* __restrict__ bias4,
                                                 float4* __restrict__ outT, int N) {
    int c = (int)(blockIdx.x & 3);
    int g = (int)(blockIdx.x >> 2);
    int idx = g * 64 + (int)(threadIdx.x >> 2);
    if (idx >= N) return;
    int v = perm[idx];
    int j = threadIdx.x & 3;
    size_t cb = (size_t)c * N;
    float4 acc = pull_body(rowptr, colu, g2T, cb, v, j);
    float dv = dinv[v];
    float4 bv = bias4[c * 4 + j];
    outT[(cb + v) * 4 + j] =
        make_float4(fmaf(acc.x, dv, bv.x), fmaf(acc.y, dv, bv.y),
                    fmaf(acc.z, dv, bv.z), fmaf(acc.w, dv, bv.w));
}

// ---------------------------------------------------------------------------
// logits part: edge-order, chunk c = blockIdx&3. 4-lane group per edge; both
// endpoint slices gathered (L2-pinned); part[c*E+e] coalesced.
// ---------------------------------------------------------------------------
__global__ __launch_bounds__(256) void logits_part_k(const int* __restrict__ src,
                                                     const int* __restrict__ dst,
                                                     const float4* __restrict__ aggT,
                                                     float* __restrict__ part,
                                                     int N, int E) {
    int c = (int)(blockIdx.x & 3);
    int blk = (int)(blockIdx.x >> 2);
    int g = (int)(threadIdx.x >> 2);
    int j = threadIdx.x & 3;
    size_t cb = (size_t)c * N;
    int ebase = blk * 256;

#pragma unroll
    for (int i = 0; i < 4; i++) {
        int e = ebase + i * 64 + g;
        if (e < E) {
            int s = src[e], d = dst[e];
            float4 a = aggT[(cb + s) * 4 + j];
            float4 b = aggT[(cb + d) * 4 + j];
            float t = a.x * b.x + a.y * b.y + a.z * b.z + a.w * b.w;
            t += __shfl_xor(t, 1);
            t += __shfl_xor(t, 2);
            if (j == 0) part[(size_t)c * E + e] = t;
        }
    }
}

// out[e] = sum of 4 chunk partials; coalesced float4 I/O.
__global__ __launch_bounds__(256) void logits_reduce_k(const float* __restrict__ part,
                                                       float* __restrict__ out, int E) {
    int i = blockIdx.x * blockDim.x + threadIdx.x;
    int e4 = E >> 2;
    if (i < e4) {
        const float4* p0 = reinterpret_cast<const float4*>(part);
        const float4* p1 = reinterpret_cast<const float4*>(part + (size_t)E);
        const float4* p2 = reinterpret_cast<const float4*>(part + (size_t)E * 2);
        const float4* p3 = reinterpret_cast<const float4*>(part + (size_t)E * 3);
        float4 a = p0[i], b = p1[i], c = p2[i], d = p3[i];
        float4 o = make_float4((a.x + b.x) + (c.x + d.x), (a.y + b.y) + (c.y + d.y),
                               (a.z + b.z) + (c.z + d.z), (a.w + b.w) + (c.w + d.w));
        reinterpret_cast<float4*>(out)[i] = o;
    }
    if (blockIdx.x == 0 && threadIdx.x < (E & 3)) {
        int e = e4 * 4 + threadIdx.x;
        out[e] = part[e] + part[(size_t)E + e] + part[(size_t)E * 2 + e] +
                 part[(size_t)E * 3 + e];
    }
}

extern "C" void kernel_launch(void* const* d_in, const int* in_sizes, int n_in,
                              void* d_out, int out_size, void* d_ws, size_t ws_size,
                              hipStream_t stream) {
    const float* x  = (const float*)d_in[0];
    const int* ei   = (const int*)d_in[1];   // int32 (harness converts ints)
    const float* W1 = (const float*)d_in[2];
    const float* b1 = (const float*)d_in[3];
    const float* W2 = (const float*)d_in[4];
    const float* b2 = (const float*)d_in[5];
    float* out = (float*)d_out;

    const int N = in_sizes[0] / 128;   // 50000 (< 65536 -> ushort col valid)
    const int E = in_sizes[1] / 2;     // 800000
    const int* src = ei;
    const int* dst = ei + E;

    // ---- workspace ----
    // floats: dinv[50176] | bufA[N*128] | bufB[N*128]
    //   hsT   = bufA             (chunked [8][N][16])
    //   agg1  = bufB             (linear; dead after gemm2)
    //   g2T   = bufA[0,  N*64)   (chunked [4][N][16])
    //   agg2T = bufA[N*64,N*128) (chunked [4][N][16])
    //   part  = bufB[0, 4E)      (overlays dead agg1)
    // ints: cnt[N] | hist[1024] | hcur[1024] | incl[N] | rowptr[N+1] | bsum[256]
    //       | perm[N] | rank[E] | colu[E] (ushort)
    float* ws    = (float*)d_ws;
    float* dinv  = ws;
    float* bufA  = ws + 50176;
    float* bufB  = bufA + (size_t)N * 128;
    float* hsT   = bufA;
    float* agg1  = bufB;
    float* g2T   = bufA;
    float* agg2T = bufA + (size_t)N * 64;
    float* part  = bufB;

    int* ibase  = (int*)(bufB + (size_t)N * 128);
    int* cnt    = ibase;
    int* hist   = cnt + N;
    int* hcur   = hist + 1024;
    int* incl   = hcur + 1024;
    int* rowptr = incl + N;
    int* bsum   = rowptr + (N + 1);
    int* perm   = bsum + 256;
    int* rank   = perm + N;
    ushort_t* colu = (ushort_t*)(rank + E);

    const int B = 256;
    const int NB = (N + 255) / 256;                  // 196
    const unsigned ng64 = (unsigned)((N + 63) / 64); // 782

    // ---- CSR count (+rank) + scans (+degree histogram/perm) ----
    hipMemsetAsync(cnt, 0, ((size_t)N + 1024) * sizeof(int), stream);  // cnt+hist
    cnt_rank_k<<<(E / 4 + B - 1) / B, B, 0, stream>>>(dst, cnt, rank, E);
    scan1_k<<<NB, 256, 0, stream>>>(cnt, incl, bsum, hist, N);
    hscan_k<<<1, 1024, 0, stream>>>(hist, hcur);
    scan23_k<<<NB, 256, 0, stream>>>(cnt, incl, bsum, rowptr, dinv, hcur, perm, N, E, NB);

    // ---- fused: GEMM1 (hsT chunked) + atomic-free CSR fill (ushort col) ----
    {
        int gemmBlocks = (N + 31) / 32;              // 1563
        int fillBlocks = (E / 4 + B - 1) / B;        // 782
        gemm1_fill_k<<<gemmBlocks + fillBlocks, 256, 0, stream>>>(
            x, W1, dinv, (float4*)hsT, N, N, src, dst, rowptr, rank, colu, E,
            gemmBlocks);
    }

    // ---- layer 1 pull (8 chunks x 782 node-groups, degree-sorted) ----
    pull128c_k<<<ng64 * 8, 256, 0, stream>>>(rowptr, colu, perm, (const float4*)hsT,
                                             dinv, (const float4*)b1, (float4*)agg1, N);

    // ---- layer 2 GEMM -> g2T chunked ----
    gemm2_k<<<(N + 31) / 32, 256, 0, stream>>>(agg1, W2, dinv, (float4*)g2T, N, N);

    // ---- layer 2 pull (4 chunks x 782 node-groups, degree-sorted) ----
    pull64c_k<<<ng64 * 4, 256, 0, stream>>>(rowptr, colu, perm, (const float4*)g2T,
                                            dinv, (const float4*)b2, (float4*)agg2T, N);

    // ---- logits: edge-order chunked partials + reduce ----
    {
        unsigned blk = (unsigned)((E + 255) / 256);       // 3125
        logits_part_k<<<blk * 4, 256, 0, stream>>>(src, dst, (const float4*)agg2T,
                                                   part, N, E);
        unsigned rblk = (unsigned)((E / 4 + 255) / 256);  // 782
        logits_reduce_k<<<rblk, 256, 0, stream>>>(part, out, E);
    }
}

// Round 19
// 212.880 us; speedup vs baseline: 2.0991x; 2.0991x over previous
//
#include <hip/hip_runtime.h>
#include <hip/hip_bf16.h>

// ---------------------------------------------------------------------------
// GCN 2-layer + edge dot logits, CSR-pull aggregation.
// agg[d] = dinv[d] * ( sum_{s in in(d)} hs[s] + hs[d] ) + b,  hs = (A@W)*dinv[row]
// Round 19: r17 structure (XCD-chunked tables, lane-group pulls, edge-order
// logits, atomic-free fill, ushort col). NEW: CSR segments padded to x8 with
// filler index N pointing at a zeroed table row -> pull loops are uniform
// (no tails/predicates) and 8 indices load as ONE uint4. (r18's degree-sort
// reverted: same-address atomic-return scatter cost 110us.)
// ---------------------------------------------------------------------------

using ushort_t = unsigned short;

// count + per-edge rank within its dst segment (atomic returns old count)
__global__ void cnt_rank_k(const int* __restrict__ dst, int* __restrict__ cnt,
                           int* __restrict__ rank, int E) {
    int t = blockIdx.x * blockDim.x + threadIdx.x;
    int e = t * 4;
    if (e + 4 <= E) {
        int4 d4 = *reinterpret_cast<const int4*>(dst + e);
        int4 r4;
        r4.x = atomicAdd(&cnt[d4.x], 1);
        r4.y = atomicAdd(&cnt[d4.y], 1);
        r4.z = atomicAdd(&cnt[d4.z], 1);
        r4.w = atomicAdd(&cnt[d4.w], 1);
        *reinterpret_cast<int4*>(rank + e) = r4;   // coalesced
    } else {
        for (int i = e; i < E; i++) rank[i] = atomicAdd(&cnt[dst[i]], 1);
    }
}

// block scan over PADDED counts ((deg+7)&~7)
__global__ void scan1_k(const int* __restrict__ cnt, int* __restrict__ incl,
                        int* __restrict__ bsum, int N) {
    __shared__ int sh[256];
    int i = blockIdx.x * 256 + threadIdx.x;
    int v = (i < N) ? ((cnt[i] + 7) & ~7) : 0;
    sh[threadIdx.x] = v;
    __syncthreads();
#pragma unroll
    for (int off = 1; off < 256; off <<= 1) {
        int t = (threadIdx.x >= off) ? sh[threadIdx.x - off] : 0;
        __syncthreads();
        sh[threadIdx.x] += t;
        __syncthreads();
    }
    if (i < N) incl[i] = sh[threadIdx.x];
    if (threadIdx.x == 255) bsum[blockIdx.x] = sh[255];
}

// fused scan2+scan3: rowptr (padded), dinv, pad-filler colu entries, rowptr[N].
__global__ __launch_bounds__(256) void scan23_k(const int* __restrict__ cnt,
                                                const int* __restrict__ incl,
                                                const int* __restrict__ bsum,
                                                int* __restrict__ rowptr,
                                                float* __restrict__ dinv,
                                                ushort_t* __restrict__ colu,
                                                int N, int NB) {
    __shared__ int sh[256];
    __shared__ int blockOff, totalPad;
    int v = (threadIdx.x < NB) ? bsum[threadIdx.x] : 0;
    sh[threadIdx.x] = v;
    __syncthreads();
#pragma unroll
    for (int off = 1; off < 256; off <<= 1) {
        int t = (threadIdx.x >= off) ? sh[threadIdx.x - off] : 0;
        __syncthreads();
        sh[threadIdx.x] += t;
        __syncthreads();
    }
    if (threadIdx.x == blockIdx.x) blockOff = sh[threadIdx.x] - v;  // exclusive
    if (threadIdx.x == NB - 1) totalPad = sh[threadIdx.x];          // grand total
    __syncthreads();
    int i = blockIdx.x * 256 + threadIdx.x;
    if (i < N) {
        int c = cnt[i];
        int cp = (c + 7) & ~7;
        int excl = incl[i] - cp + blockOff;
        rowptr[i] = excl;
        dinv[i] = rsqrtf(1.0f + (float)c);  // +1 self-loop
        for (int k = c; k < cp; k++) colu[excl + k] = (ushort_t)N;  // filler
    }
    if (i == 0) rowptr[N] = totalPad;
}

// ---------------------------------------------------------------------------
// GEMM body, BM=32, BK=16, 256 threads (conflict-free LDS maps).
// Output CHUNK-TRANSPOSED: OutT[chunk][Np][16] (row N of each chunk = filler).
// ---------------------------------------------------------------------------
template <int BN, bool RELU>
__device__ __forceinline__ void gemm_body32(const float* __restrict__ A,
                                            const float* __restrict__ W,
                                            const float* __restrict__ dscale,
                                            float4* __restrict__ OutT,
                                            int M, int Np, int row0,
                                            float (*As)[36], float (*Bs)[BN]) {
    constexpr int K = 128, BK = 16;
    constexpr int TN = BN / 16;  // 8 (BN=128) or 4 (BN=64)
    const int tid = threadIdx.x;
    const int tx = tid & 15, ty = tid >> 4;

    float acc[2][TN];
#pragma unroll
    for (int m = 0; m < 2; m++)
#pragma unroll
        for (int n = 0; n < TN; n++) acc[m][n] = 0.0f;

    for (int kt = 0; kt < K; kt += BK) {
        if (tid < 128) {
            int r = tid >> 2;
            int kq = (tid & 3) * 4;
            float4 av = make_float4(0.f, 0.f, 0.f, 0.f);
            int gr = row0 + r;
            if (gr < M)
                av = *reinterpret_cast<const float4*>(A + (size_t)gr * K + kt + kq);
            if (RELU) {
                av.x = fmaxf(av.x, 0.f); av.y = fmaxf(av.y, 0.f);
                av.z = fmaxf(av.z, 0.f); av.w = fmaxf(av.w, 0.f);
            }
            As[kq + 0][r] = av.x; As[kq + 1][r] = av.y;
            As[kq + 2][r] = av.z; As[kq + 3][r] = av.w;
        }
#pragma unroll
        for (int s = 0; s < (BK * BN) / (256 * 4); s++) {
            int f = s * 256 + tid;
            int brow = f / (BN / 4);
            int bcol = (f % (BN / 4)) * 4;
            float4 bv = *reinterpret_cast<const float4*>(W + (size_t)(kt + brow) * BN + bcol);
            *reinterpret_cast<float4*>(&Bs[brow][bcol]) = bv;
        }
        __syncthreads();

#pragma unroll
        for (int k = 0; k < BK; k++) {
            float2 a2 = *reinterpret_cast<const float2*>(&As[k][ty * 2]);
            float a[2] = {a2.x, a2.y};
            float b[TN];
            float4 b0 = *reinterpret_cast<const float4*>(&Bs[k][tx * 4]);
            b[0] = b0.x; b[1] = b0.y; b[2] = b0.z; b[3] = b0.w;
            if (TN == 8) {
                float4 b1 = *reinterpret_cast<const float4*>(&Bs[k][64 + tx * 4]);
                b[4] = b1.x; b[5] = b1.y; b[6] = b1.z; b[7] = b1.w;
            }
#pragma unroll
            for (int m = 0; m < 2; m++)
#pragma unroll
                for (int n = 0; n < TN; n++) acc[m][n] = fmaf(a[m], b[n], acc[m][n]);
        }
        __syncthreads();
    }

    const int chunk0 = tx >> 2;
    const int off = tx & 3;
#pragma unroll
    for (int m = 0; m < 2; m++) {
        int gr = row0 + ty * 2 + m;
        if (gr < M) {
            float dv = dscale[gr];
            float4 o0 = make_float4(acc[m][0] * dv, acc[m][1] * dv,
                                    acc[m][2] * dv, acc[m][3] * dv);
            OutT[((size_t)chunk0 * Np + gr) * 4 + off] = o0;
            if (TN == 8) {
                float4 o1 = make_float4(acc[m][4] * dv, acc[m][5] * dv,
                                        acc[m][6] * dv, acc[m][7] * dv);
                OutT[((size_t)(4 + chunk0) * Np + gr) * 4 + off] = o1;
            }
        }
    }
}

// ---------------------------------------------------------------------------
// FUSED: blocks [0,gemmBlocks) = GEMM1 -> hsT chunked (+ block 0 zeroes filler
// row N); rest = atomic-free CSR fill: colu[rowptr[dst]+rank] = (ushort)src.
// ---------------------------------------------------------------------------
__global__ __launch_bounds__(256) void gemm1_fill_k(const float* __restrict__ A,
                                                    const float* __restrict__ W,
                                                    const float* __restrict__ dscale,
                                                    float4* __restrict__ OutT,
                                                    int M, int Np,
                                                    const int* __restrict__ src,
                                                    const int* __restrict__ dst,
                                                    const int* __restrict__ rowptr,
                                                    const int* __restrict__ rank,
                                                    ushort_t* __restrict__ colu, int E,
                                                    int gemmBlocks) {
    __shared__ float As[16][36];
    __shared__ float Bs[16][128];
    int g = (int)blockIdx.x;
    if (g >= gemmBlocks) {
        int t = (g - gemmBlocks) * 256 + threadIdx.x;
        int e = t * 4;
        if (e + 4 <= E) {
            int4 s4 = *reinterpret_cast<const int4*>(src + e);
            int4 d4 = *reinterpret_cast<const int4*>(dst + e);
            int4 r4 = *reinterpret_cast<const int4*>(rank + e);
            colu[rowptr[d4.x] + r4.x] = (ushort_t)s4.x;
            colu[rowptr[d4.y] + r4.y] = (ushort_t)s4.y;
            colu[rowptr[d4.z] + r4.z] = (ushort_t)s4.z;
            colu[rowptr[d4.w] + r4.w] = (ushort_t)s4.w;
        } else {
            for (int i = e; i < E; i++)
                colu[rowptr[dst[i]] + rank[i]] = (ushort_t)src[i];
        }
        return;
    }
    if (g == 0 && threadIdx.x < 32) {  // zero filler row N of all 8 chunks
        int c = threadIdx.x >> 2, q4 = threadIdx.x & 3;
        OutT[((size_t)c * Np + (Np - 1)) * 4 + q4] = make_float4(0.f, 0.f, 0.f, 0.f);
    }
    gemm_body32<128, false>(A, W, dscale, OutT, M, Np, g * 32, As, Bs);
}

__global__ __launch_bounds__(256) void gemm2_k(const float* __restrict__ A,
                                               const float* __restrict__ W,
                                               const float* __restrict__ dscale,
                                               float4* __restrict__ OutT,
                                               int M, int Np) {
    __shared__ float As[16][36];
    __shared__ float Bs[16][64];
    if (blockIdx.x == 0 && threadIdx.x < 16) {  // zero filler row of 4 chunks
        int c = threadIdx.x >> 2, q4 = threadIdx.x & 3;
        OutT[((size_t)c * Np + (Np - 1)) * 4 + q4] = make_float4(0.f, 0.f, 0.f, 0.f);
    }
    gemm_body32<64, true>(A, W, dscale, OutT, M, Np, (int)blockIdx.x * 32, As, Bs);
}

// ---------------------------------------------------------------------------
// Chunked pull body (padded CSR): segments are x8, 8-aligned; 8 indices load
// as ONE uint4; filler index Np-1 hits the zeroed row. 1-block lookahead.
// ---------------------------------------------------------------------------
__device__ __forceinline__ float4 pull_body(const int* __restrict__ rowptr,
                                            const ushort_t* __restrict__ colu,
                                            const float4* __restrict__ T,
                                            size_t cb, int v, int j) {
    int p0 = rowptr[v], p1 = rowptr[v + 1];
    float4 acc = T[(cb + v) * 4 + j];  // self row slice
    int nb = (p1 - p0) >> 3;
    if (nb == 0) return acc;

    const uint4* cp = reinterpret_cast<const uint4*>(colu + p0);  // 16B aligned
    uint4 ci = cp[0];
    for (int ib = 0; ib < nb; ib++) {
        bool more = (ib + 1 < nb);
        uint4 cn;
        if (more) cn = cp[ib + 1];   // prefetch next 8 indices
        int n0 = ci.x & 0xFFFF, n1 = ci.x >> 16;
        int n2 = ci.y & 0xFFFF, n3 = ci.y >> 16;
        int n4 = ci.z & 0xFFFF, n5 = ci.z >> 16;
        int n6 = ci.w & 0xFFFF, n7 = ci.w >> 16;
        float4 g0 = T[(cb + n0) * 4 + j];
        float4 g1 = T[(cb + n1) * 4 + j];
        float4 g2 = T[(cb + n2) * 4 + j];
        float4 g3 = T[(cb + n3) * 4 + j];
        float4 g4 = T[(cb + n4) * 4 + j];
        float4 g5 = T[(cb + n5) * 4 + j];
        float4 g6 = T[(cb + n6) * 4 + j];
        float4 g7 = T[(cb + n7) * 4 + j];
        acc.x += ((g0.x + g1.x) + (g2.x + g3.x)) + ((g4.x + g5.x) + (g6.x + g7.x));
        acc.y += ((g0.y + g1.y) + (g2.y + g3.y)) + ((g4.y + g5.y) + (g6.y + g7.y));
        acc.z += ((g0.z + g1.z) + (g2.z + g3.z)) + ((g4.z + g5.z) + (g6.z + g7.z));
        acc.w += ((g0.w + g1.w) + (g2.w + g3.w)) + ((g4.w + g5.w) + (g6.w + g7.w));
        ci = cn;
    }
    return acc;
}

// pull128: blockIdx = g*8 + c -> chunk c (XCD c). Output agg1 LINEAR [N][128].
__global__ __launch_bounds__(256) void pull128c_k(const int* __restrict__ rowptr,
                                                  const ushort_t* __restrict__ colu,
                                                  const float4* __restrict__ hsT,
                                                  const float* __restrict__ dinv,
                                                  const float4* __restrict__ bias4,
                                                  float4* __restrict__ out4,
                                                  int N, int Np) {
    int c = (int)(blockIdx.x & 7);
    int g = (int)(blockIdx.x >> 3);
    int v = g * 64 + (int)(threadIdx.x >> 2);
    if (v >= N) return;
    int j = threadIdx.x & 3;
    float4 acc = pull_body(rowptr, colu, hsT, (size_t)c * Np, v, j);
    float dv = dinv[v];
    float4 bv = bias4[c * 4 + j];
    out4[(size_t)v * 32 + c * 4 + j] =
        make_float4(fmaf(acc.x, dv, bv.x), fmaf(acc.y, dv, bv.y),
                    fmaf(acc.z, dv, bv.z), fmaf(acc.w, dv, bv.w));
}

// pull64: blockIdx = g*4 + c (slice on XCDs c,c+4). Reads g2T (stride Np),
// writes agg2T CHUNKED [4][N][16] (stride N).
__global__ __launch_bounds__(256) void pull64c_k(const int* __restrict__ rowptr,
                                                 const ushort_t* __restrict__ colu,
                                                 const float4* __restrict__ g2T,
                                                 const float* __restrict__ dinv,
                                                 const float4* __restrict__ bias4,
                                                 float4* __restrict__ outT,
                                                 int N, int Np) {
    int c = (int)(blockIdx.x & 3);
    int g = (int)(blockIdx.x >> 2);
    int v = g * 64 + (int)(threadIdx.x >> 2);
    if (v >= N) return;
    int j = threadIdx.x & 3;
    float4 acc = pull_body(rowptr, colu, g2T, (size_t)c * Np, v, j);
    float dv = dinv[v];
    float4 bv = bias4[c * 4 + j];
    outT[((size_t)c * N + v) * 4 + j] =
        make_float4(fmaf(acc.x, dv, bv.x), fmaf(acc.y, dv, bv.y),
                    fmaf(acc.z, dv, bv.z), fmaf(acc.w, dv, bv.w));
}

// ---------------------------------------------------------------------------
// logits part: edge-order, chunk c = blockIdx&3; part[c*E+e] coalesced.
// ---------------------------------------------------------------------------
__global__ __launch_bounds__(256) void logits_part_k(const int* __restrict__ src,
                                                     const int* __restrict__ dst,
                                                     const float4* __restrict__ aggT,
                                                     float* __restrict__ part,
                                                     int N, int E) {
    int c = (int)(blockIdx.x & 3);
    int blk = (int)(blockIdx.x >> 2);
    int g = (int)(threadIdx.x >> 2);
    int j = threadIdx.x & 3;
    size_t cb = (size_t)c * N;
    int ebase = blk * 256;

#pragma unroll
    for (int i = 0; i < 4; i++) {
        int e = ebase + i * 64 + g;
        if (e < E) {
            int s = src[e], d = dst[e];
            float4 a = aggT[(cb + s) * 4 + j];
            float4 b = aggT[(cb + d) * 4 + j];
            float t = a.x * b.x + a.y * b.y + a.z * b.z + a.w * b.w;
            t += __shfl_xor(t, 1);
            t += __shfl_xor(t, 2);
            if (j == 0) part[(size_t)c * E + e] = t;
        }
    }
}

// out[e] = sum of 4 chunk partials; coalesced float4 I/O.
__global__ __launch_bounds__(256) void logits_reduce_k(const float* __restrict__ part,
                                                       float* __restrict__ out, int E) {
    int i = blockIdx.x * blockDim.x + threadIdx.x;
    int e4 = E >> 2;
    if (i < e4) {
        const float4* p0 = reinterpret_cast<const float4*>(part);
        const float4* p1 = reinterpret_cast<const float4*>(part + (size_t)E);
        const float4* p2 = reinterpret_cast<const float4*>(part + (size_t)E * 2);
        const float4* p3 = reinterpret_cast<const float4*>(part + (size_t)E * 3);
        float4 a = p0[i], b = p1[i], c = p2[i], d = p3[i];
        float4 o = make_float4((a.x + b.x) + (c.x + d.x), (a.y + b.y) + (c.y + d.y),
                               (a.z + b.z) + (c.z + d.z), (a.w + b.w) + (c.w + d.w));
        reinterpret_cast<float4*>(out)[i] = o;
    }
    if (blockIdx.x == 0 && threadIdx.x < (E & 3)) {
        int e = e4 * 4 + threadIdx.x;
        out[e] = part[e] + part[(size_t)E + e] + part[(size_t)E * 2 + e] +
                 part[(size_t)E * 3 + e];
    }
}

extern "C" void kernel_launch(void* const* d_in, const int* in_sizes, int n_in,
                              void* d_out, int out_size, void* d_ws, size_t ws_size,
                              hipStream_t stream) {
    const float* x  = (const float*)d_in[0];
    const int* ei   = (const int*)d_in[1];   // int32 (harness converts ints)
    const float* W1 = (const float*)d_in[2];
    const float* b1 = (const float*)d_in[3];
    const float* W2 = (const float*)d_in[4];
    const float* b2 = (const float*)d_in[5];
    float* out = (float*)d_out;

    const int N = in_sizes[0] / 128;   // 50000 (< 65535 -> ushort col valid)
    const int E = in_sizes[1] / 2;     // 800000
    const int Np = N + 1;              // tables have filler row N (zeros)
    const int* src = ei;
    const int* dst = ei + E;

    // ---- workspace ----
    // floats: dinv[50176] | regionA[(N+1)*128] | regionB[N*128]
    //   hsT   = regionA              (chunked [8][Np][16])
    //   g2T   = regionA[0, 4*Np*16)  (chunked [4][Np][16]; hsT dead)
    //   agg2T = regionA + 4*Np*16    (chunked [4][N][16])
    //   agg1  = regionB (linear [N][128]); part = regionB (agg1 dead)
    // ints: cnt[N] | incl[N] | rowptr[N+1] | bsum[256] | rank[E] | colu[E+8N]
    float* ws      = (float*)d_ws;
    float* dinv    = ws;
    float* regionA = ws + 50176;
    float* regionB = regionA + (size_t)Np * 128;
    float* hsT     = regionA;
    float* g2T     = regionA;
    float* agg2T   = regionA + (size_t)4 * Np * 16;
    float* agg1    = regionB;
    float* part    = regionB;

    int* ibase  = (int*)(regionB + (size_t)N * 128);
    int* cnt    = ibase;
    int* incl   = cnt + N;
    int* rowptr = incl + N;
    int* bsum   = rowptr + (N + 1);
    int* rank   = bsum + 256;
    ushort_t* colu = (ushort_t*)(((uintptr_t)(rank + E) + 15) & ~(uintptr_t)15);

    const int B = 256;
    const int NB = (N + 255) / 256;                  // 196
    const unsigned ng64 = (unsigned)((N + 63) / 64); // 782

    // ---- CSR count (+rank) + scans (padded) ----
    hipMemsetAsync(cnt, 0, (size_t)N * sizeof(int), stream);
    cnt_rank_k<<<(E / 4 + B - 1) / B, B, 0, stream>>>(dst, cnt, rank, E);
    scan1_k<<<NB, 256, 0, stream>>>(cnt, incl, bsum, N);
    scan23_k<<<NB, 256, 0, stream>>>(cnt, incl, bsum, rowptr, dinv, colu, N, NB);

    // ---- fused: GEMM1 (hsT chunked, zero filler row) + CSR fill ----
    {
        int gemmBlocks = (N + 31) / 32;              // 1563
        int fillBlocks = (E / 4 + B - 1) / B;        // 782
        gemm1_fill_k<<<gemmBlocks + fillBlocks, 256, 0, stream>>>(
            x, W1, dinv, (float4*)hsT, N, Np, src, dst, rowptr, rank, colu, E,
            gemmBlocks);
    }

    // ---- layer 1 pull (8 chunks x 782 node-groups) -> agg1 linear ----
    pull128c_k<<<ng64 * 8, 256, 0, stream>>>(rowptr, colu, (const float4*)hsT,
                                             dinv, (const float4*)b1,
                                             (float4*)agg1, N, Np);

    // ---- layer 2 GEMM -> g2T chunked (zero filler row) ----
    gemm2_k<<<(N + 31) / 32, 256, 0, stream>>>(agg1, W2, dinv, (float4*)g2T, N, Np);

    // ---- layer 2 pull (4 chunks x 782 node-groups) -> agg2T chunked ----
    pull64c_k<<<ng64 * 4, 256, 0, stream>>>(rowptr, colu, (const float4*)g2T,
                                            dinv, (const float4*)b2,
                                            (float4*)agg2T, N, Np);

    // ---- logits: edge-order chunked partials + reduce ----
    {
        unsigned blk = (unsigned)((E + 255) / 256);       // 3125
        logits_part_k<<<blk * 4, 256, 0, stream>>>(src, dst, (const float4*)agg2T,
                                                   part, N, E);
        unsigned rblk = (unsigned)((E / 4 + 255) / 256);  // 782
        logits_reduce_k<<<rblk, 256, 0, stream>>>(part, out, E);
    }
}

// Round 20
// 210.349 us; speedup vs baseline: 2.1244x; 1.0120x over previous
//
#include <hip/hip_runtime.h>
#include <hip/hip_bf16.h>

// ---------------------------------------------------------------------------
// GCN 2-layer + edge dot logits, CSR-pull aggregation.
// agg[d] = dinv[d] * ( sum_{s in in(d)} hs[s] + hs[d] ) + b,  hs = (A@W)*dinv[row]
// Round 20: r19 + agg1 stored CHUNKED [8][N][16] so pull128c's output writes
// are coalesced (was 16x scattered 64B half-lines per wave -> write-allocate
// RMW on 25.6MB). gemm2's A-stage reads the chunked layout natively: BK=16
// k-tiles map 1:1 to chunks. Everything else = r19 (padded x8 CSR, uint4
// index loads, XCD-pinned slices, atomic-free fill, edge-order logits).
// ---------------------------------------------------------------------------

using ushort_t = unsigned short;

// count + per-edge rank within its dst segment (atomic returns old count)
__global__ void cnt_rank_k(const int* __restrict__ dst, int* __restrict__ cnt,
                           int* __restrict__ rank, int E) {
    int t = blockIdx.x * blockDim.x + threadIdx.x;
    int e = t * 4;
    if (e + 4 <= E) {
        int4 d4 = *reinterpret_cast<const int4*>(dst + e);
        int4 r4;
        r4.x = atomicAdd(&cnt[d4.x], 1);
        r4.y = atomicAdd(&cnt[d4.y], 1);
        r4.z = atomicAdd(&cnt[d4.z], 1);
        r4.w = atomicAdd(&cnt[d4.w], 1);
        *reinterpret_cast<int4*>(rank + e) = r4;   // coalesced
    } else {
        for (int i = e; i < E; i++) rank[i] = atomicAdd(&cnt[dst[i]], 1);
    }
}

// block scan over PADDED counts ((deg+7)&~7)
__global__ void scan1_k(const int* __restrict__ cnt, int* __restrict__ incl,
                        int* __restrict__ bsum, int N) {
    __shared__ int sh[256];
    int i = blockIdx.x * 256 + threadIdx.x;
    int v = (i < N) ? ((cnt[i] + 7) & ~7) : 0;
    sh[threadIdx.x] = v;
    __syncthreads();
#pragma unroll
    for (int off = 1; off < 256; off <<= 1) {
        int t = (threadIdx.x >= off) ? sh[threadIdx.x - off] : 0;
        __syncthreads();
        sh[threadIdx.x] += t;
        __syncthreads();
    }
    if (i < N) incl[i] = sh[threadIdx.x];
    if (threadIdx.x == 255) bsum[blockIdx.x] = sh[255];
}

// fused scan2+scan3: rowptr (padded), dinv, pad-filler colu entries, rowptr[N].
__global__ __launch_bounds__(256) void scan23_k(const int* __restrict__ cnt,
                                                const int* __restrict__ incl,
                                                const int* __restrict__ bsum,
                                                int* __restrict__ rowptr,
                                                float* __restrict__ dinv,
                                                ushort_t* __restrict__ colu,
                                                int N, int NB) {
    __shared__ int sh[256];
    __shared__ int blockOff, totalPad;
    int v = (threadIdx.x < NB) ? bsum[threadIdx.x] : 0;
    sh[threadIdx.x] = v;
    __syncthreads();
#pragma unroll
    for (int off = 1; off < 256; off <<= 1) {
        int t = (threadIdx.x >= off) ? sh[threadIdx.x - off] : 0;
        __syncthreads();
        sh[threadIdx.x] += t;
        __syncthreads();
    }
    if (threadIdx.x == blockIdx.x) blockOff = sh[threadIdx.x] - v;  // exclusive
    if (threadIdx.x == NB - 1) totalPad = sh[threadIdx.x];          // grand total
    __syncthreads();
    int i = blockIdx.x * 256 + threadIdx.x;
    if (i < N) {
        int c = cnt[i];
        int cp = (c + 7) & ~7;
        int excl = incl[i] - cp + blockOff;
        rowptr[i] = excl;
        dinv[i] = rsqrtf(1.0f + (float)c);  // +1 self-loop
        for (int k = c; k < cp; k++) colu[excl + k] = (ushort_t)N;  // filler
    }
    if (i == 0) rowptr[N] = totalPad;
}

// ---------------------------------------------------------------------------
// GEMM body, BM=32, BK=16, 256 threads (conflict-free LDS maps).
// A input: linear [M][128] (CA=false) or chunked [8][Na][16] (CA=true; each
// BK=16 k-tile kt lies entirely in chunk kt/16 -> coalesced float4 loads).
// Output CHUNK-TRANSPOSED: OutT[chunk][Np][16].
// ---------------------------------------------------------------------------
template <int BN, bool RELU, bool CA>
__device__ __forceinline__ void gemm_body32(const float* __restrict__ A,
                                            const float* __restrict__ W,
                                            const float* __restrict__ dscale,
                                            float4* __restrict__ OutT,
                                            int M, int Np, int Na, int row0,
                                            float (*As)[36], float (*Bs)[BN]) {
    constexpr int K = 128, BK = 16;
    constexpr int TN = BN / 16;  // 8 (BN=128) or 4 (BN=64)
    const int tid = threadIdx.x;
    const int tx = tid & 15, ty = tid >> 4;

    float acc[2][TN];
#pragma unroll
    for (int m = 0; m < 2; m++)
#pragma unroll
        for (int n = 0; n < TN; n++) acc[m][n] = 0.0f;

    for (int kt = 0; kt < K; kt += BK) {
        if (tid < 128) {
            int r = tid >> 2;
            int kq = (tid & 3) * 4;
            float4 av = make_float4(0.f, 0.f, 0.f, 0.f);
            int gr = row0 + r;
            if (gr < M) {
                if (CA)
                    av = *reinterpret_cast<const float4*>(
                        A + ((size_t)(kt >> 4) * Na + gr) * 16 + kq);
                else
                    av = *reinterpret_cast<const float4*>(A + (size_t)gr * K + kt + kq);
            }
            if (RELU) {
                av.x = fmaxf(av.x, 0.f); av.y = fmaxf(av.y, 0.f);
                av.z = fmaxf(av.z, 0.f); av.w = fmaxf(av.w, 0.f);
            }
            As[kq + 0][r] = av.x; As[kq + 1][r] = av.y;
            As[kq + 2][r] = av.z; As[kq + 3][r] = av.w;
        }
#pragma unroll
        for (int s = 0; s < (BK * BN) / (256 * 4); s++) {
            int f = s * 256 + tid;
            int brow = f / (BN / 4);
            int bcol = (f % (BN / 4)) * 4;
            float4 bv = *reinterpret_cast<const float4*>(W + (size_t)(kt + brow) * BN + bcol);
            *reinterpret_cast<float4*>(&Bs[brow][bcol]) = bv;
        }
        __syncthreads();

#pragma unroll
        for (int k = 0; k < BK; k++) {
            float2 a2 = *reinterpret_cast<const float2*>(&As[k][ty * 2]);
            float a[2] = {a2.x, a2.y};
            float b[TN];
            float4 b0 = *reinterpret_cast<const float4*>(&Bs[k][tx * 4]);
            b[0] = b0.x; b[1] = b0.y; b[2] = b0.z; b[3] = b0.w;
            if (TN == 8) {
                float4 b1 = *reinterpret_cast<const float4*>(&Bs[k][64 + tx * 4]);
                b[4] = b1.x; b[5] = b1.y; b[6] = b1.z; b[7] = b1.w;
            }
#pragma unroll
            for (int m = 0; m < 2; m++)
#pragma unroll
                for (int n = 0; n < TN; n++) acc[m][n] = fmaf(a[m], b[n], acc[m][n]);
        }
        __syncthreads();
    }

    const int chunk0 = tx >> 2;
    const int off = tx & 3;
#pragma unroll
    for (int m = 0; m < 2; m++) {
        int gr = row0 + ty * 2 + m;
        if (gr < M) {
            float dv = dscale[gr];
            float4 o0 = make_float4(acc[m][0] * dv, acc[m][1] * dv,
                                    acc[m][2] * dv, acc[m][3] * dv);
            OutT[((size_t)chunk0 * Np + gr) * 4 + off] = o0;
            if (TN == 8) {
                float4 o1 = make_float4(acc[m][4] * dv, acc[m][5] * dv,
                                        acc[m][6] * dv, acc[m][7] * dv);
                OutT[((size_t)(4 + chunk0) * Np + gr) * 4 + off] = o1;
            }
        }
    }
}

// ---------------------------------------------------------------------------
// FUSED: blocks [0,gemmBlocks) = GEMM1 -> hsT chunked (+ block 0 zeroes filler
// row N); rest = atomic-free CSR fill: colu[rowptr[dst]+rank] = (ushort)src.
// ---------------------------------------------------------------------------
__global__ __launch_bounds__(256) void gemm1_fill_k(const float* __restrict__ A,
                                                    const float* __restrict__ W,
                                                    const float* __restrict__ dscale,
                                                    float4* __restrict__ OutT,
                                                    int M, int Np,
                                                    const int* __restrict__ src,
                                                    const int* __restrict__ dst,
                                                    const int* __restrict__ rowptr,
                                                    const int* __restrict__ rank,
                                                    ushort_t* __restrict__ colu, int E,
                                                    int gemmBlocks) {
    __shared__ float As[16][36];
    __shared__ float Bs[16][128];
    int g = (int)blockIdx.x;
    if (g >= gemmBlocks) {
        int t = (g - gemmBlocks) * 256 + threadIdx.x;
        int e = t * 4;
        if (e + 4 <= E) {
            int4 s4 = *reinterpret_cast<const int4*>(src + e);
            int4 d4 = *reinterpret_cast<const int4*>(dst + e);
            int4 r4 = *reinterpret_cast<const int4*>(rank + e);
            colu[rowptr[d4.x] + r4.x] = (ushort_t)s4.x;
            colu[rowptr[d4.y] + r4.y] = (ushort_t)s4.y;
            colu[rowptr[d4.z] + r4.z] = (ushort_t)s4.z;
            colu[rowptr[d4.w] + r4.w] = (ushort_t)s4.w;
        } else {
            for (int i = e; i < E; i++)
                colu[rowptr[dst[i]] + rank[i]] = (ushort_t)src[i];
        }
        return;
    }
    if (g == 0 && threadIdx.x < 32) {  // zero filler row N of all 8 chunks
        int c = threadIdx.x >> 2, q4 = threadIdx.x & 3;
        OutT[((size_t)c * Np + (Np - 1)) * 4 + q4] = make_float4(0.f, 0.f, 0.f, 0.f);
    }
    gemm_body32<128, false, false>(A, W, dscale, OutT, M, Np, 0, g * 32, As, Bs);
}

// gemm2: A = agg1T chunked [8][N][16] (relu'd on load); out g2T chunked [4][Np][16].
__global__ __launch_bounds__(256) void gemm2_k(const float* __restrict__ AT,
                                               const float* __restrict__ W,
                                               const float* __restrict__ dscale,
                                               float4* __restrict__ OutT,
                                               int M, int Np, int Na) {
    __shared__ float As[16][36];
    __shared__ float Bs[16][64];
    if (blockIdx.x == 0 && threadIdx.x < 16) {  // zero filler row of 4 chunks
        int c = threadIdx.x >> 2, q4 = threadIdx.x & 3;
        OutT[((size_t)c * Np + (Np - 1)) * 4 + q4] = make_float4(0.f, 0.f, 0.f, 0.f);
    }
    gemm_body32<64, true, true>(AT, W, dscale, OutT, M, Np, Na, (int)blockIdx.x * 32,
                                As, Bs);
}

// ---------------------------------------------------------------------------
// Chunked pull body (padded CSR): segments x8, 8-aligned; 8 indices = 1 uint4;
// filler index Np-1 hits the zeroed row. 1-block index lookahead.
// ---------------------------------------------------------------------------
__device__ __forceinline__ float4 pull_body(const int* __restrict__ rowptr,
                                            const ushort_t* __restrict__ colu,
                                            const float4* __restrict__ T,
                                            size_t cb, int v, int j) {
    int p0 = rowptr[v], p1 = rowptr[v + 1];
    float4 acc = T[(cb + v) * 4 + j];  // self row slice
    int nb = (p1 - p0) >> 3;
    if (nb == 0) return acc;

    const uint4* cp = reinterpret_cast<const uint4*>(colu + p0);  // 16B aligned
    uint4 ci = cp[0];
    for (int ib = 0; ib < nb; ib++) {
        bool more = (ib + 1 < nb);
        uint4 cn;
        if (more) cn = cp[ib + 1];   // prefetch next 8 indices
        int n0 = ci.x & 0xFFFF, n1 = ci.x >> 16;
        int n2 = ci.y & 0xFFFF, n3 = ci.y >> 16;
        int n4 = ci.z & 0xFFFF, n5 = ci.z >> 16;
        int n6 = ci.w & 0xFFFF, n7 = ci.w >> 16;
        float4 g0 = T[(cb + n0) * 4 + j];
        float4 g1 = T[(cb + n1) * 4 + j];
        float4 g2 = T[(cb + n2) * 4 + j];
        float4 g3 = T[(cb + n3) * 4 + j];
        float4 g4 = T[(cb + n4) * 4 + j];
        float4 g5 = T[(cb + n5) * 4 + j];
        float4 g6 = T[(cb + n6) * 4 + j];
        float4 g7 = T[(cb + n7) * 4 + j];
        acc.x += ((g0.x + g1.x) + (g2.x + g3.x)) + ((g4.x + g5.x) + (g6.x + g7.x));
        acc.y += ((g0.y + g1.y) + (g2.y + g3.y)) + ((g4.y + g5.y) + (g6.y + g7.y));
        acc.z += ((g0.z + g1.z) + (g2.z + g3.z)) + ((g4.z + g5.z) + (g6.z + g7.z));
        acc.w += ((g0.w + g1.w) + (g2.w + g3.w)) + ((g4.w + g5.w) + (g6.w + g7.w));
        ci = cn;
    }
    return acc;
}

// pull128: blockIdx = g*8 + c -> chunk c (XCD c). Output agg1T CHUNKED
// [8][N][16] -> 16 consecutive nodes/wave = 1KB contiguous store.
__global__ __launch_bounds__(256) void pull128c_k(const int* __restrict__ rowptr,
                                                  const ushort_t* __restrict__ colu,
                                                  const float4* __restrict__ hsT,
                                                  const float* __restrict__ dinv,
                                                  const float4* __restrict__ bias4,
                                                  float4* __restrict__ out1T,
                                                  int N, int Np) {
    int c = (int)(blockIdx.x & 7);
    int g = (int)(blockIdx.x >> 3);
    int v = g * 64 + (int)(threadIdx.x >> 2);
    if (v >= N) return;
    int j = threadIdx.x & 3;
    float4 acc = pull_body(rowptr, colu, hsT, (size_t)c * Np, v, j);
    float dv = dinv[v];
    float4 bv = bias4[c * 4 + j];
    out1T[((size_t)c * N + v) * 4 + j] =
        make_float4(fmaf(acc.x, dv, bv.x), fmaf(acc.y, dv, bv.y),
                    fmaf(acc.z, dv, bv.z), fmaf(acc.w, dv, bv.w));
}

// pull64: blockIdx = g*4 + c (slice on XCDs c,c+4). Reads g2T (stride Np),
// writes agg2T CHUNKED [4][N][16].
__global__ __launch_bounds__(256) void pull64c_k(const int* __restrict__ rowptr,
                                                 const ushort_t* __restrict__ colu,
                                                 const float4* __restrict__ g2T,
                                                 const float* __restrict__ dinv,
                                                 const float4* __restrict__ bias4,
                                                 float4* __restrict__ outT,
                                                 int N, int Np) {
    int c = (int)(blockIdx.x & 3);
    int g = (int)(blockIdx.x >> 2);
    int v = g * 64 + (int)(threadIdx.x >> 2);
    if (v >= N) return;
    int j = threadIdx.x & 3;
    float4 acc = pull_body(rowptr, colu, g2T, (size_t)c * Np, v, j);
    float dv = dinv[v];
    float4 bv = bias4[c * 4 + j];
    outT[((size_t)c * N + v) * 4 + j] =
        make_float4(fmaf(acc.x, dv, bv.x), fmaf(acc.y, dv, bv.y),
                    fmaf(acc.z, dv, bv.z), fmaf(acc.w, dv, bv.w));
}

// ---------------------------------------------------------------------------
// logits part: edge-order, chunk c = blockIdx&3; part[c*E+e] coalesced.
// ---------------------------------------------------------------------------
__global__ __launch_bounds__(256) void logits_part_k(const int* __restrict__ src,
                                                     const int* __restrict__ dst,
                                                     const float4* __restrict__ aggT,
                                                     float* __restrict__ part,
                                                     int N, int E) {
    int c = (int)(blockIdx.x & 3);
    int blk = (int)(blockIdx.x >> 2);
    int g = (int)(threadIdx.x >> 2);
    int j = threadIdx.x & 3;
    size_t cb = (size_t)c * N;
    int ebase = blk * 256;

#pragma unroll
    for (int i = 0; i < 4; i++) {
        int e = ebase + i * 64 + g;
        if (e < E) {
            int s = src[e], d = dst[e];
            float4 a = aggT[(cb + s) * 4 + j];
            float4 b = aggT[(cb + d) * 4 + j];
            float t = a.x * b.x + a.y * b.y + a.z * b.z + a.w * b.w;
            t += __shfl_xor(t, 1);
            t += __shfl_xor(t, 2);
            if (j == 0) part[(size_t)c * E + e] = t;
        }
    }
}

// out[e] = sum of 4 chunk partials; coalesced float4 I/O.
__global__ __launch_bounds__(256) void logits_reduce_k(const float* __restrict__ part,
                                                       float* __restrict__ out, int E) {
    int i = blockIdx.x * blockDim.x + threadIdx.x;
    int e4 = E >> 2;
    if (i < e4) {
        const float4* p0 = reinterpret_cast<const float4*>(part);
        const float4* p1 = reinterpret_cast<const float4*>(part + (size_t)E);
        const float4* p2 = reinterpret_cast<const float4*>(part + (size_t)E * 2);
        const float4* p3 = reinterpret_cast<const float4*>(part + (size_t)E * 3);
        float4 a = p0[i], b = p1[i], c = p2[i], d = p3[i];
        float4 o = make_float4((a.x + b.x) + (c.x + d.x), (a.y + b.y) + (c.y + d.y),
                               (a.z + b.z) + (c.z + d.z), (a.w + b.w) + (c.w + d.w));
        reinterpret_cast<float4*>(out)[i] = o;
    }
    if (blockIdx.x == 0 && threadIdx.x < (E & 3)) {
        int e = e4 * 4 + threadIdx.x;
        out[e] = part[e] + part[(size_t)E + e] + part[(size_t)E * 2 + e] +
                 part[(size_t)E * 3 + e];
    }
}

extern "C" void kernel_launch(void* const* d_in, const int* in_sizes, int n_in,
                              void* d_out, int out_size, void* d_ws, size_t ws_size,
                              hipStream_t stream) {
    const float* x  = (const float*)d_in[0];
    const int* ei   = (const int*)d_in[1];   // int32 (harness converts ints)
    const float* W1 = (const float*)d_in[2];
    const float* b1 = (const float*)d_in[3];
    const float* W2 = (const float*)d_in[4];
    const float* b2 = (const float*)d_in[5];
    float* out = (float*)d_out;

    const int N = in_sizes[0] / 128;   // 50000 (< 65535 -> ushort col valid)
    const int E = in_sizes[1] / 2;     // 800000
    const int Np = N + 1;              // gather tables have zeroed filler row N
    const int* src = ei;
    const int* dst = ei + E;

    // ---- workspace ----
    // floats: dinv[50176] | regionA[(N+1)*128] | regionB[N*128]
    //   hsT   = regionA              (chunked [8][Np][16])
    //   g2T   = regionA[0, 4*Np*16)  (chunked [4][Np][16]; hsT dead)
    //   agg2T = regionA + 4*Np*16    (chunked [4][N][16])
    //   agg1T = regionB              (chunked [8][N][16]; dead after gemm2)
    //   part  = regionB              (overlays dead agg1T)
    // ints: cnt[N] | incl[N] | rowptr[N+1] | bsum[256] | rank[E] | colu[E+8N]
    float* ws      = (float*)d_ws;
    float* dinv    = ws;
    float* regionA = ws + 50176;
    float* regionB = regionA + (size_t)Np * 128;
    float* hsT     = regionA;
    float* g2T     = regionA;
    float* agg2T   = regionA + (size_t)4 * Np * 16;
    float* agg1T   = regionB;
    float* part    = regionB;

    int* ibase  = (int*)(regionB + (size_t)N * 128);
    int* cnt    = ibase;
    int* incl   = cnt + N;
    int* rowptr = incl + N;
    int* bsum   = rowptr + (N + 1);
    int* rank   = bsum + 256;
    ushort_t* colu = (ushort_t*)(((uintptr_t)(rank + E) + 15) & ~(uintptr_t)15);

    const int B = 256;
    const int NB = (N + 255) / 256;                  // 196
    const unsigned ng64 = (unsigned)((N + 63) / 64); // 782

    // ---- CSR count (+rank) + scans (padded) ----
    hipMemsetAsync(cnt, 0, (size_t)N * sizeof(int), stream);
    cnt_rank_k<<<(E / 4 + B - 1) / B, B, 0, stream>>>(dst, cnt, rank, E);
    scan1_k<<<NB, 256, 0, stream>>>(cnt, incl, bsum, N);
    scan23_k<<<NB, 256, 0, stream>>>(cnt, incl, bsum, rowptr, dinv, colu, N, NB);

    // ---- fused: GEMM1 (hsT chunked, zero filler row) + CSR fill ----
    {
        int gemmBlocks = (N + 31) / 32;              // 1563
        int fillBlocks = (E / 4 + B - 1) / B;        // 782
        gemm1_fill_k<<<gemmBlocks + fillBlocks, 256, 0, stream>>>(
            x, W1, dinv, (float4*)hsT, N, Np, src, dst, rowptr, rank, colu, E,
            gemmBlocks);
    }

    // ---- layer 1 pull (8 chunks x 782 node-groups) -> agg1T CHUNKED ----
    pull128c_k<<<ng64 * 8, 256, 0, stream>>>(rowptr, colu, (const float4*)hsT,
                                             dinv, (const float4*)b1,
                                             (float4*)agg1T, N, Np);

    // ---- layer 2 GEMM (chunked A) -> g2T chunked (zero filler row) ----
    gemm2_k<<<(N + 31) / 32, 256, 0, stream>>>(agg1T, W2, dinv, (float4*)g2T, N, Np, N);

    // ---- layer 2 pull (4 chunks x 782 node-groups) -> agg2T chunked ----
    pull64c_k<<<ng64 * 4, 256, 0, stream>>>(rowptr, colu, (const float4*)g2T,
                                            dinv, (const float4*)b2,
                                            (float4*)agg2T, N, Np);

    // ---- logits: edge-order chunked partials + reduce ----
    {
        unsigned blk = (unsigned)((E + 255) / 256);       // 3125
        logits_part_k<<<blk * 4, 256, 0, stream>>>(src, dst, (const float4*)agg2T,
                                                   part, N, E);
        unsigned rblk = (unsigned)((E / 4 + 255) / 256);  // 782
        logits_reduce_k<<<rblk, 256, 0, stream>>>(part, out, E);
    }
}